// Round 1
// baseline (241.923 us; speedup 1.0000x reference)
//
#include <hip/hip_runtime.h>

// Circle (ball) projection: out = center + (x-center) * min(1, R/max(||x-center||,1e-12))
// B = 8,388,608 points, 3 fp32 coords each, AoS layout [B,3].
// Memory-bound: 288 MiB total traffic -> target ~50 us at ~6.3 TB/s.
//
// Each thread handles 4 points = 12 floats = 3 float4 loads per operand.
// B*3/12 = 2,097,152 threads = 8192 blocks x 256 (exact, no tail — but guarded).

#define RADIUS 1.0f

__global__ __launch_bounds__(256) void circle_proj_kernel(
    const float4* __restrict__ xv,
    const float4* __restrict__ cv,
    float4* __restrict__ ov,
    int ngroups)  // number of 4-point groups
{
    int t = blockIdx.x * blockDim.x + threadIdx.x;
    if (t >= ngroups) return;
    long base = (long)t * 3;

    float4 x0 = xv[base + 0];
    float4 x1 = xv[base + 1];
    float4 x2 = xv[base + 2];
    float4 c0 = cv[base + 0];
    float4 c1 = cv[base + 1];
    float4 c2 = cv[base + 2];

    float px[12] = {x0.x, x0.y, x0.z, x0.w, x1.x, x1.y, x1.z, x1.w, x2.x, x2.y, x2.z, x2.w};
    float pc[12] = {c0.x, c0.y, c0.z, c0.w, c1.x, c1.y, c1.z, c1.w, c2.x, c2.y, c2.z, c2.w};
    float po[12];

#pragma unroll
    for (int p = 0; p < 4; ++p) {
        float dx = px[3*p + 0] - pc[3*p + 0];
        float dy = px[3*p + 1] - pc[3*p + 1];
        float dz = px[3*p + 2] - pc[3*p + 2];
        float n2 = dx*dx + dy*dy + dz*dz;
        float n  = sqrtf(n2);
        float denom = fmaxf(n, 1e-12f);
        float scale = fminf(1.0f, RADIUS / denom);
        po[3*p + 0] = pc[3*p + 0] + dx * scale;
        po[3*p + 1] = pc[3*p + 1] + dy * scale;
        po[3*p + 2] = pc[3*p + 2] + dz * scale;
    }

    float4 o0 = {po[0], po[1], po[2],  po[3]};
    float4 o1 = {po[4], po[5], po[6],  po[7]};
    float4 o2 = {po[8], po[9], po[10], po[11]};
    ov[base + 0] = o0;
    ov[base + 1] = o1;
    ov[base + 2] = o2;
}

extern "C" void kernel_launch(void* const* d_in, const int* in_sizes, int n_in,
                              void* d_out, int out_size, void* d_ws, size_t ws_size,
                              hipStream_t stream) {
    const float* x = (const float*)d_in[0];       // [B,3] fp32
    const float* c = (const float*)d_in[1];       // [B,3] fp32
    float* out = (float*)d_out;                   // [B,3] fp32

    int total_floats = in_sizes[0];               // B*3
    int ngroups = total_floats / 12;              // 4 points per thread

    int block = 256;
    int grid = (ngroups + block - 1) / block;     // 8192 for B=8388608

    circle_proj_kernel<<<grid, block, 0, stream>>>(
        (const float4*)x, (const float4*)c, (float4*)out, ngroups);
}

// Round 2
// 240.966 us; speedup vs baseline: 1.0040x; 1.0040x over previous
//
#include <hip/hip_runtime.h>

// Circle (ball) projection: out = center + (x-center) * min(1, R/max(||x-center||,1e-12))
// B = 8,388,608 points, 3 fp32 coords, AoS [B,3].
//
// R1 change: the R0 kernel loaded 3 float4/thread at a 48 B per-instruction
// lane stride (AoS stride-3) -> each wave load touched ~48 cache lines
// instead of 16 (3x transaction inflation), capping effective BW at ~3.1 TB/s.
// Fix: LDS block transpose. Globals are accessed with lane-contiguous float4
// instructions only; the stride-3 access happens in LDS where the b128 reads
// at float4-index stride 3 distribute evenly over all 8 bank groups
// (gcd(3,8)=1) -> expected near-conflict-free.
//
// Tile: 768 float4 = 3072 floats = 1024 points per block of 256 threads
// (4 points/thread). nf4 = 6,291,456 -> exactly 8192 tiles, no remainder
// (tail kernel provided for safety, not launched at this size).

#define RADIUS 1.0f

__global__ __launch_bounds__(256) void circle_proj_lds(
    const float4* __restrict__ xv,
    const float4* __restrict__ cv,
    float4* __restrict__ ov)
{
    __shared__ float4 sx[768];
    __shared__ float4 sc[768];

    const int tid = threadIdx.x;
    const long base = (long)blockIdx.x * 768 + tid;

    // Phase 1: coalesced global -> LDS (identity layout)
#pragma unroll
    for (int k = 0; k < 3; ++k) {
        sx[k*256 + tid] = xv[base + k*256];
        sc[k*256 + tid] = cv[base + k*256];
    }
    __syncthreads();

    // Phase 2: each thread pulls its 4 points (12 consecutive floats) from LDS
    float4 x0 = sx[3*tid + 0], x1 = sx[3*tid + 1], x2 = sx[3*tid + 2];
    float4 c0 = sc[3*tid + 0], c1 = sc[3*tid + 1], c2 = sc[3*tid + 2];

    float px[12] = {x0.x, x0.y, x0.z, x0.w, x1.x, x1.y, x1.z, x1.w, x2.x, x2.y, x2.z, x2.w};
    float pc[12] = {c0.x, c0.y, c0.z, c0.w, c1.x, c1.y, c1.z, c1.w, c2.x, c2.y, c2.z, c2.w};
    float po[12];

#pragma unroll
    for (int p = 0; p < 4; ++p) {
        float dx = px[3*p + 0] - pc[3*p + 0];
        float dy = px[3*p + 1] - pc[3*p + 1];
        float dz = px[3*p + 2] - pc[3*p + 2];
        float n2 = dx*dx + dy*dy + dz*dz;
        float n  = sqrtf(n2);
        float denom = fmaxf(n, 1e-12f);
        float scale = fminf(1.0f, RADIUS / denom);
        po[3*p + 0] = pc[3*p + 0] + dx * scale;
        po[3*p + 1] = pc[3*p + 1] + dy * scale;
        po[3*p + 2] = pc[3*p + 2] + dz * scale;
    }

    // Phase 3: results back through LDS (reuse sx), then coalesced stores
    __syncthreads();
    sx[3*tid + 0] = make_float4(po[0], po[1], po[2],  po[3]);
    sx[3*tid + 1] = make_float4(po[4], po[5], po[6],  po[7]);
    sx[3*tid + 2] = make_float4(po[8], po[9], po[10], po[11]);
    __syncthreads();

#pragma unroll
    for (int k = 0; k < 3; ++k) {
        ov[base + k*256] = sx[k*256 + tid];
    }
}

// Safety tail: one thread per point, scalar loads (only launched if the
// element count isn't a multiple of the 1024-point tile — not hit at B=8M).
__global__ __launch_bounds__(256) void circle_proj_tail(
    const float* __restrict__ x,
    const float* __restrict__ c,
    float* __restrict__ o,
    long start_pt, long npts)
{
    long p = start_pt + blockIdx.x * blockDim.x + threadIdx.x;
    if (p >= npts) return;
    float dx = x[3*p+0] - c[3*p+0];
    float dy = x[3*p+1] - c[3*p+1];
    float dz = x[3*p+2] - c[3*p+2];
    float n = sqrtf(dx*dx + dy*dy + dz*dz);
    float scale = fminf(1.0f, RADIUS / fmaxf(n, 1e-12f));
    o[3*p+0] = c[3*p+0] + dx * scale;
    o[3*p+1] = c[3*p+1] + dy * scale;
    o[3*p+2] = c[3*p+2] + dz * scale;
}

extern "C" void kernel_launch(void* const* d_in, const int* in_sizes, int n_in,
                              void* d_out, int out_size, void* d_ws, size_t ws_size,
                              hipStream_t stream) {
    const float* x = (const float*)d_in[0];   // [B,3] fp32
    const float* c = (const float*)d_in[1];   // [B,3] fp32
    float* out = (float*)d_out;

    long total_floats = in_sizes[0];          // B*3 = 25,165,824
    long nf4 = total_floats / 4;              // 6,291,456
    long ntiles = nf4 / 768;                  // 8192 (exact at this size)

    if (ntiles > 0) {
        circle_proj_lds<<<(int)ntiles, 256, 0, stream>>>(
            (const float4*)x, (const float4*)c, (float4*)out);
    }

    long pts_done = ntiles * 1024;
    long npts = total_floats / 3;
    if (pts_done < npts) {
        long rem = npts - pts_done;
        int grid = (int)((rem + 255) / 256);
        circle_proj_tail<<<grid, 256, 0, stream>>>(x, c, out, pts_done, npts);
    }
}